// Round 13
// baseline (261.797 us; speedup 1.0000x reference)
//
#include <hip/hip_runtime.h>
#include <hip/hip_bf16.h>
#include <math.h>

#define B_    16
#define N_    577
#define C_    768
#define H_    12
#define D_    64
#define M_    (B_ * N_)       // 9232
#define MP_   9344            // padded M rows in xb (73*128)
#define QKVN  2304
#define NP_   640             // padded N for Vt rows
#define SCALE 0.125f
#define ALPHA 0.1f
#define OUT0  (B_ * N_ * C_)  // 7090176 floats (out), then patch_attn

#define NB_CONV 7008          // MP_*768/4/256
#define NB_T1   1728          // (2304/32)*(768/32)
#define NB_T2   576           // (768/32)*(768/32)

typedef __attribute__((ext_vector_type(8))) short short8;
typedef __attribute__((ext_vector_type(4))) float f32x4;
typedef __hip_bfloat16 bf16;

__device__ __forceinline__ float exp2fast(float x) {
    return __builtin_amdgcn_exp2f(x);   // v_exp_f32 (base 2)
}

__device__ __forceinline__ void load16(const void* g, void* l) {
    __builtin_amdgcn_global_load_lds(
        (const __attribute__((address_space(1))) unsigned int*)g,
        (__attribute__((address_space(3))) unsigned int*)l, 16, 0, 0);
}

__device__ __forceinline__ f32x4 mfma16(short8 a, short8 b, f32x4 c) {
    return __builtin_amdgcn_mfma_f32_16x16x32_bf16(a, b, c, 0, 0, 0);
}

#define FENCE() asm volatile("" ::: "memory")
#define BARRIER() do { FENCE(); __builtin_amdgcn_s_barrier(); FENCE(); } while (0)

// ---------------- fused prep: conv_x + transpose(w_qkv) + transpose(w_proj)
__global__ __launch_bounds__(256) void prep(const float* __restrict__ x,
                                            bf16* __restrict__ xb,
                                            const float* __restrict__ wq,
                                            bf16* __restrict__ wqT,
                                            const float* __restrict__ wp,
                                            bf16* __restrict__ wpT) {
    __shared__ float tile[32][33];
    const int bid = blockIdx.x;
    if (bid < NB_CONV) {
        int idx = bid * 256 + threadIdx.x;   // one per 4 elements
        int m = idx / 192;
        bf16 tmp[4];
        if (m < M_) {
            float4 f = ((const float4*)x)[idx];
            tmp[0] = __float2bfloat16(f.x);
            tmp[1] = __float2bfloat16(f.y);
            tmp[2] = __float2bfloat16(f.z);
            tmp[3] = __float2bfloat16(f.w);
        } else {
            tmp[0] = tmp[1] = tmp[2] = tmp[3] = __float2bfloat16(0.f);
        }
        ((ushort4*)xb)[idx] = *(ushort4*)tmp;
        return;
    }
    const float* src; bf16* dst; int C, R, bx, by;
    if (bid < NB_CONV + NB_T1) {
        int r = bid - NB_CONV;
        bx = r % 72; by = r / 72; src = wq; dst = wqT; R = 768; C = QKVN;
    } else {
        int r = bid - NB_CONV - NB_T1;
        bx = r % 24; by = r / 24; src = wp; dst = wpT; R = 768; C = 768;
    }
    int cb = bx * 32, rb = by * 32;
    int tx = threadIdx.x & 31, ty = threadIdx.x >> 5;  // ty 0..7
    #pragma unroll
    for (int i = 0; i < 32; i += 8)
        tile[ty + i][tx] = src[(size_t)(rb + ty + i) * C + cb + tx];
    __syncthreads();
    #pragma unroll
    for (int i = 0; i < 32; i += 8)
        dst[(size_t)(cb + ty + i) * R + rb + tx] = __float2bfloat16(tile[tx][ty + i]);
}

// ---------------- 128x128 MFMA GEMM, BK=64, SINGLE-buffer, 4 blocks/CU.
// R8/R11-verified best (QKV 53.7-55.6us, MfmaUtil ~24%, VGPR 60).
// 256 threads = 4 waves (2M x 2N), per-wave 64x64 (acc[4][4]).  12 K-steps.
// Per step: {16 ds_read_b128 + 32 MFMA} -> BARRIER -> {stage(k+1) into the
// SAME buffer + vmcnt(0)} -> BARRIER.  4 independent blocks/CU cover each
// other's stage drains (R4/R5: TLP, not in-block pipelining, is what pays).
// R9 lesson: B must stay LDS-staged (direct per-lane global B-frags scatter
// 32 lines/load -> 98us).  R10 lesson: __launch_bounds__(512,6) capped VGPR
// at 85 -> acc spilled to scratch (VGPR=40, 1.6GB traffic, 414us); this
// kernel's (256,4) cap is 128 VGPR, actual 60, no spill.
// Race-freedom:
//  (a) barrier #1 after the MFMAs: every wave's ds_reads of the buffer were
//      consumed (compiler lgkm waits before MFMA) before any wave stages.
//  (b) vmcnt(0) + barrier #2 publishes all waves' staged slices.
// LDS swizzle: rows 128B; physical granule = logical ^ (row&7), applied via
// pre-swizzled GLOBAL source (linear gload_lds dest) + swizzled ds_read addr
// (conflict-verified: 23K).  Bijective XCD swizzle (m204).
// R12: container failed twice (infra, no kernel error; R6 precedent --
// unchanged resubmission recovered).  Audit found no hang/OOB path.
__global__ __launch_bounds__(256, 4) void gemm128(const bf16* __restrict__ A,
                                                  const bf16* __restrict__ BT,
                                                  const float* __restrict__ bias,
                                                  bf16* __restrict__ q,
                                                  bf16* __restrict__ kk,
                                                  bf16* __restrict__ vt,
                                                  float* __restrict__ out,
                                                  int mode, int nby) {
    __shared__ __align__(16) char smem[35840];
    // A tile [128 rows][128B] at +0, B tile at +16384; Tt epilogue aliases all.

    const int nwg = gridDim.x;
    const int orig = blockIdx.x;
    const int xcd = orig & 7, ii = orig >> 3;
    const int qq = nwg >> 3, rr = nwg & 7;
    const int wg = (xcd < rr ? xcd * (qq + 1) : rr * (qq + 1) + (xcd - rr) * qq) + ii;
    const int mb = wg / nby;
    const int nb = wg - mb * nby;
    const int m0 = mb * 128, n0 = nb * 128;
    const int t = threadIdx.x, lane = t & 63, w = t >> 6;
    const int wr = w >> 1, wc = w & 1;
    const int r16 = lane & 15, quad = lane >> 4;

    f32x4 acc[4][4];
    #pragma unroll
    for (int i = 0; i < 4; i++)
        #pragma unroll
        for (int j = 0; j < 4; j++) acc[i][j] = (f32x4)(0.f);

    // staging: wave w writes tile bytes [w*4096, +4096) per operand, lane-linear.
    // LDS byte L = w*4096 + i*1024 + lane*16 -> row = w*32+i*8+(lane>>3),
    // phys granule = lane&7.  Source granule = (lane&7) ^ (row&7), row&7 = lane>>3.
    const int lrow = lane >> 3;
    const int clog = ((lane & 7) ^ lrow) << 4;
    const char* gA = (const char*)A  + (size_t)(m0 + w * 32 + lrow) * 1536 + clog;
    const char* gB = (const char*)BT + (size_t)(n0 + w * 32 + lrow) * 1536 + clog;

    auto stage = [&](int k2) {   // 8 loads: full A+B K-slab k2 -> the single buf
        const int kc = k2 * 128;
        #pragma unroll
        for (int i = 0; i < 4; i++) {
            char* dA = (char*)smem + w * 4096 + i * 1024;
            load16(gA + (size_t)i * 12288 + kc, dA);
            load16(gB + (size_t)i * 12288 + kc, dA + 16384);
        }
    };

    stage(0);
    asm volatile("s_waitcnt vmcnt(0)" ::: "memory");
    BARRIER();

    // read swizzle: logical granule g at row r sits at physical g ^ (r16&7)
    const int sw = r16 & 7;
    const int g0 = (quad ^ sw) << 4;          // kk0: logical granules 0..3
    const int g1 = ((quad ^ 4) ^ sw) << 4;    // kk1: logical granules 4..7

    #pragma unroll 1
    for (int k = 0; k < 12; k++) {
        const char* Ap = (const char*)smem + (wr * 64 + r16) * 128;
        const char* Bp = (const char*)smem + 16384 + (wc * 64 + r16) * 128;

        short8 a[4], b[4];
        #pragma unroll
        for (int mi = 0; mi < 4; mi++) a[mi] = *(const short8*)(Ap + mi * 2048 + g0);
        #pragma unroll
        for (int nj = 0; nj < 4; nj++) b[nj] = *(const short8*)(Bp + nj * 2048 + g0);
        __builtin_amdgcn_s_setprio(1);
        #pragma unroll
        for (int mi = 0; mi < 4; mi++)
            #pragma unroll
            for (int nj = 0; nj < 4; nj++)
                acc[mi][nj] = mfma16(a[mi], b[nj], acc[mi][nj]);
        __builtin_amdgcn_s_setprio(0);

        #pragma unroll
        for (int mi = 0; mi < 4; mi++) a[mi] = *(const short8*)(Ap + mi * 2048 + g1);
        #pragma unroll
        for (int nj = 0; nj < 4; nj++) b[nj] = *(const short8*)(Bp + nj * 2048 + g1);
        __builtin_amdgcn_s_setprio(1);
        #pragma unroll
        for (int mi = 0; mi < 4; mi++)
            #pragma unroll
            for (int nj = 0; nj < 4; nj++)
                acc[mi][nj] = mfma16(a[mi], b[nj], acc[mi][nj]);
        __builtin_amdgcn_s_setprio(0);

        BARRIER();                 // all waves' reads of the buffer retired
        if (k < 11) {
            stage(k + 1);          // overwrite the single buffer
            asm volatile("s_waitcnt vmcnt(0)" ::: "memory");
            BARRIER();             // publish all waves' slices
        }
    }

    float bs[4];
    #pragma unroll
    for (int nj = 0; nj < 4; nj++) bs[nj] = bias[n0 + wc * 64 + nj * 16 + r16];

    if (mode == 1) {
        #pragma unroll
        for (int mi = 0; mi < 4; mi++) {
            #pragma unroll
            for (int nj = 0; nj < 4; nj++) {
                #pragma unroll
                for (int r = 0; r < 4; r++) {
                    int m = m0 + wr * 64 + mi * 16 + quad * 4 + r;
                    if (m >= M_) continue;
                    int cc = n0 + wc * 64 + nj * 16 + r16;
                    out[(size_t)m * 768 + cc] = acc[mi][nj][r] + bs[nj];
                }
            }
        }
        return;
    }

    // ---- mode 0: pack C^T into Tt (col-major, pad 140), then scatter (proven)
    bf16* Tt = (bf16*)smem;                 // [128 cc][140 m], aliases the buffer
    #pragma unroll
    for (int mi = 0; mi < 4; mi++) {
        #pragma unroll
        for (int nj = 0; nj < 4; nj++) {
            bf16 pk[4];
            #pragma unroll
            for (int r = 0; r < 4; r++)
                pk[r] = __float2bfloat16(acc[mi][nj][r] + bs[nj]);
            int ccl = wc * 64 + nj * 16 + r16;
            int ml4 = wr * 64 + mi * 16 + quad * 4;
            *(uint2*)&Tt[ccl * 140 + ml4] = *(const uint2*)pk;
        }
    }
    __syncthreads();

    const int part = nb / 6;     // 0:q 1:k 2:v (128-col blocks, 6 per part)
    if (part < 2) {
        // q/k: thread = (half, row). dst rows contiguous across n for fixed (b,h).
        int nl = t & 127, half = t >> 7;
        int m = m0 + nl;
        if (m < M_) {
            int b = m / N_, n = m - b * N_;
            int h = (nb % 6) * 2 + half;
            bf16* dst = (part == 0 ? q : kk) + ((size_t)(b * H_ + h) * N_ + n) * 64;
            #pragma unroll
            for (int d8 = 0; d8 < 8; d8++) {
                bf16 tv[8];
                #pragma unroll
                for (int dd = 0; dd < 8; dd++)
                    tv[dd] = Tt[(half * 64 + d8 * 8 + dd) * 140 + nl];
                *(uint4*)(dst + d8 * 8) = *(const uint4*)tv;
            }
        }
    } else {
        // v: thread = (d-row, 64-col segment); runs contiguous in n with peeling
        int dr = t >> 1, seg = t & 1;
        int rem = (nb % 6) * 128 + dr;   // global v-col = h*64+d
        int h = rem >> 6, d = rem & 63;
        int mb2 = m0 + seg * 64;
        int b = mb2 / N_;
        int n = mb2 - b * N_;
        const bf16* src = Tt + dr * 140 + seg * 64;
        int i = 0;
        while (i < 64 && mb2 + i < M_) {
            if (n == N_) { b++; n = 0; }
            bf16* drow = vt + ((size_t)(b * H_ + h) * 64 + d) * NP_;
            if ((n & 7) == 0 && n + 8 <= N_ && i + 8 <= 64 && mb2 + i + 8 <= M_) {
                bf16 tv[8];
                #pragma unroll
                for (int dd = 0; dd < 8; dd++) tv[dd] = src[i + dd];
                *(uint4*)(drow + n) = *(const uint4*)tv;
                i += 8; n += 8;
            } else {
                drow[n] = src[i]; i++; n++;
            }
        }
    }
}

// ---------------- flash attention, MFMA, SINGLE-buffer K/V (R12/R13).
// R11 counters: attn = 54.2us, VALU 37 / MFMA 13 / HBM 8.5 / Occ 16%,
// LDS 48KB -> 3 blocks/CU = 768 slots < 960 blocks -> 1.25 dispatch rounds
// with a low-occupancy tail.  Fix (R5 precedent): single-buffer K/V ->
// LDS 8+8+16 = 32KB -> 4 blocks/CU (VGPR 112 < 128 cap) -> 1024 slots >=
// 960 blocks: WHOLE grid co-resident, tail gone; cross-block TLP covers
// the now-exposed stage.  Sync: compute -> __syncthreads (drains vmcnt +
// retires all K/V reads) -> stage(kt+1) same buffers -> __syncthreads
// (publishes).  Pb is per-wave (no cross-wave hazard).  Compute, swizzle,
// and XCD remap (T1, R8-verified) bitwise identical.
__global__ __launch_bounds__(256, 4) void attn_mfma(const bf16* __restrict__ q,
                                                    const bf16* __restrict__ k,
                                                    const bf16* __restrict__ vt,
                                                    const float* __restrict__ aw,
                                                    bf16* __restrict__ ao,
                                                    float* __restrict__ patch) {
    __shared__ bf16 Kb[4096];       // 64 j-rows x 64 d, chunk-XOR swizzled
    __shared__ bf16 Vb[4096];       // 64 d-rows x 64 j, chunk-XOR swizzled
    __shared__ bf16 Pb[4][2048];    // per-wave 32x64 P strip
    // bijective XCD swizzle over 960 blocks: wg = (orig&7)*120 + (orig>>3);
    // bh = wg/5 (contiguous 24-head chunk per XCD), qt = wg%5 (co-XCD).
    const int orig = blockIdx.x;
    const int wg = (orig & 7) * 120 + (orig >> 3);
    const int bh = wg / 5, qt = wg - bh * 5;
    const int b = bh / H_, h = bh - b * H_;
    const int t = threadIdx.x, lane = t & 63, w = t >> 6;
    const int r16 = lane & 15, quad = lane >> 4;
    const float SC2 = SCALE * 1.44269504f;   // scale * log2(e)

    const bf16* kbp = k + (size_t)bh * N_ * 64;
    const bf16* vbp = vt + (size_t)bh * 64 * NP_;

    short8 qa0[2], qa1[2];
    #pragma unroll
    for (int mi = 0; mi < 2; mi++) {
        int qrow = qt * 128 + w * 32 + mi * 16 + r16;
        int qrc = (qrow < N_) ? qrow : (N_ - 1);
        const bf16* qp = q + ((size_t)bh * N_ + qrc) * 64 + quad * 8;
        qa0[mi] = *(const short8*)(qp);
        qa1[mi] = *(const short8*)(qp + 32);
    }

    f32x4 Oacc[2][4];
    #pragma unroll
    for (int mi = 0; mi < 2; mi++)
        #pragma unroll
        for (int d0 = 0; d0 < 4; d0++) Oacc[mi][d0] = (f32x4)(0.f);
    float lrow[2][4];
    #pragma unroll
    for (int mi = 0; mi < 2; mi++)
        #pragma unroll
        for (int rr = 0; rr < 4; rr++) lrow[mi][rr] = 0.f;

    const bool clsrow = (qt == 0) && (w == 0) && (quad == 0);

    auto stage = [&](int kt) {
        #pragma unroll
        for (int is = 0; is < 2; is++) {
            int base = is * 256 + w * 64;
            int slot = base + lane;
            int row = slot >> 3, pos = slot & 7;
            int c = pos ^ (row & 7);
            int jg = kt * 64 + row; if (jg > N_ - 1) jg = N_ - 1;
            load16(kbp + (size_t)jg * 64 + c * 8, &Kb[base * 8]);
        }
        #pragma unroll
        for (int is = 0; is < 2; is++) {
            int base = is * 256 + w * 64;
            int slot = base + lane;
            int row = slot >> 3, pos = slot & 7;
            int c = pos ^ (row & 7);
            load16(vbp + (size_t)row * NP_ + kt * 64 + c * 8, &Vb[base * 8]);
        }
    };

    stage(0);
    __syncthreads();          // drains vmcnt(0) + publishes tile 0

    for (int kt = 0; kt < 10; kt++) {
        f32x4 S[2][4];
        #pragma unroll
        for (int j0 = 0; j0 < 4; j0++) {
            int row = j0 * 16 + r16;
            const bf16* kpl = &Kb[row * 64];
            short8 kf0 = *(const short8*)(kpl + ((quad ^ (row & 7)) << 3));
            short8 kf1 = *(const short8*)(kpl + (((quad ^ 4) ^ (row & 7)) << 3));
            #pragma unroll
            for (int mi = 0; mi < 2; mi++) {
                f32x4 sa = (f32x4)(0.f);
                sa = mfma16(qa0[mi], kf0, sa);
                sa = mfma16(qa1[mi], kf1, sa);
                S[mi][j0] = sa;
            }
        }

        if (kt < 9) {
            #pragma unroll
            for (int mi = 0; mi < 2; mi++) {
                #pragma unroll
                for (int j0 = 0; j0 < 4; j0++) {
                    float wfac = 1.f;
                    if (mi == 0 && clsrow) {
                        int c = kt * 64 + j0 * 16 + r16;
                        if (c >= 1) {
                            patch[(size_t)bh * (N_ - 1) + (c - 1)] = S[0][j0][0] * SCALE;
                            wfac = aw[b * (N_ - 1) + (c - 1)] * ALPHA + (1.f - ALPHA);
                        }
                    }
                    #pragma unroll
                    for (int rr = 0; rr < 4; rr++) {
                        float v = S[mi][j0][rr] * SC2;
                        if (rr == 0) v *= wfac;
                        float p = exp2fast(v);
                        S[mi][j0][rr] = p;
                        lrow[mi][rr] += p;
                    }
                }
            }
        } else {
            #pragma unroll
            for (int mi = 0; mi < 2; mi++) {
                #pragma unroll
                for (int j0 = 0; j0 < 4; j0++) {
                    int c = kt * 64 + j0 * 16 + r16;
                    bool valid = (c < N_);
                    float wfac = 1.f;
                    if (mi == 0 && clsrow && valid) {
                        patch[(size_t)bh * (N_ - 1) + (c - 1)] = S[0][j0][0] * SCALE;
                        wfac = aw[b * (N_ - 1) + (c - 1)] * ALPHA + (1.f - ALPHA);
                    }
                    #pragma unroll
                    for (int rr = 0; rr < 4; rr++) {
                        float v = S[mi][j0][rr] * SC2;
                        if (rr == 0) v *= wfac;
                        float p = valid ? exp2fast(v) : 0.f;
                        S[mi][j0][rr] = p;
                        lrow[mi][rr] += p;
                    }
                }
            }
        }

        bf16* pw = &Pb[w][0];
        #pragma unroll
        for (int mi = 0; mi < 2; mi++) {
            #pragma unroll
            for (int j0 = 0; j0 < 4; j0++) {
                int cg = j0 * 2 + (r16 >> 3);
                #pragma unroll
                for (int rr = 0; rr < 4; rr++) {
                    int rp = mi * 16 + quad * 4 + rr;
                    pw[rp * 64 + ((cg ^ (rp & 7)) << 3) + (r16 & 7)] =
                        __float2bfloat16(S[mi][j0][rr]);
                }
            }
        }
        short8 pa0[2], pa1[2];
        #pragma unroll
        for (int mi = 0; mi < 2; mi++) {
            int rp = mi * 16 + r16;
            const bf16* pr = pw + rp * 64;
            pa0[mi] = *(const short8*)(pr + ((quad ^ (rp & 7)) << 3));
            pa1[mi] = *(const short8*)(pr + (((quad ^ 4) ^ (rp & 7)) << 3));
        }

        #pragma unroll
        for (int d0 = 0; d0 < 4; d0++) {
            int row = d0 * 16 + r16;
            const bf16* vpl = &Vb[row * 64];
            short8 vf0 = *(const short8*)(vpl + ((quad ^ (row & 7)) << 3));
            short8 vf1 = *(const short8*)(vpl + (((quad ^ 4) ^ (row & 7)) << 3));
            #pragma unroll
            for (int mi = 0; mi < 2; mi++) {
                Oacc[mi][d0] = mfma16(pa0[mi], vf0, Oacc[mi][d0]);
                Oacc[mi][d0] = mfma16(pa1[mi], vf1, Oacc[mi][d0]);
            }
        }

        __syncthreads();          // all waves' K/V reads retired
        if (kt < 9) {
            stage(kt + 1);        // overwrite the single buffers
            __syncthreads();      // drains vmcnt + publishes tile kt+1
        }
    }

    #pragma unroll
    for (int mi = 0; mi < 2; mi++) {
        #pragma unroll
        for (int rr = 0; rr < 4; rr++) {
            float l = lrow[mi][rr];
            l += __shfl_xor(l, 1);
            l += __shfl_xor(l, 2);
            l += __shfl_xor(l, 4);
            l += __shfl_xor(l, 8);
            int n = qt * 128 + w * 32 + mi * 16 + quad * 4 + rr;
            if (n >= N_) continue;
            float inv = 1.f / l;
            #pragma unroll
            for (int d0 = 0; d0 < 4; d0++) {
                ao[((size_t)(b * N_ + n) * H_ + h) * 64 + d0 * 16 + r16] =
                    __float2bfloat16(Oacc[mi][d0][rr] * inv);
            }
        }
    }
}

extern "C" void kernel_launch(void* const* d_in, const int* in_sizes, int n_in,
                              void* d_out, int out_size, void* d_ws, size_t ws_size,
                              hipStream_t stream) {
    const float* x      = (const float*)d_in[0];
    const float* aw     = (const float*)d_in[1];
    const float* w_qkv  = (const float*)d_in[2];
    const float* b_qkv  = (const float*)d_in[3];
    const float* w_proj = (const float*)d_in[4];
    const float* b_proj = (const float*)d_in[5];
    float* out = (float*)d_out;

    char* ws = (char*)d_ws;
    bf16* xbf    = (bf16*)(ws);                 // MP x 768 (aliased as ao later)
    bf16* wqkvT  = (bf16*)(ws + 14352384);      // 2304 x 768
    bf16* wprojT = (bf16*)(ws + 17891328);      // 768 x 768
    bf16* qv     = (bf16*)(ws + 19070976);      // (b,h,n,d)
    bf16* kv     = (bf16*)(ws + 33251328);      // (b,h,n,d)
    bf16* vt     = (bf16*)(ws + 47431680);      // (b,h,d,NP)  -> end 63160320
    bf16* ao     = xbf;                          // WAR-safe alias (stream order)

    prep<<<NB_CONV + NB_T1 + NB_T2, 256, 0, stream>>>(x, xbf, w_qkv, wqkvT, w_proj, wprojT);

    // 128^2 tiles: QKV = 73 m-tiles x 18 n-tiles; proj = 73 x 6
    gemm128<<<73 * 18, 256, 0, stream>>>(
        xbf, wqkvT, b_qkv, qv, kv, vt, nullptr, 0, 18);

    // attn: 1D grid, 960 blocks (bh x qt), XCD-swizzled inside the kernel
    attn_mfma<<<H_ * B_ * 5, 256, 0, stream>>>(qv, kv, vt, aw, ao, out + OUT0);

    gemm128<<<73 * 6, 256, 0, stream>>>(
        ao, wprojT, b_proj, nullptr, nullptr, nullptr, out, 1, 6);
}

// Round 14
// 204.508 us; speedup vs baseline: 1.2801x; 1.2801x over previous
//
#include <hip/hip_runtime.h>
#include <hip/hip_bf16.h>
#include <math.h>

#define B_    16
#define N_    577
#define C_    768
#define H_    12
#define D_    64
#define M_    (B_ * N_)       // 9232
#define MP_   9344            // padded M rows in xb (73*128)
#define QKVN  2304
#define NP_   640             // padded N for Vt rows
#define SCALE 0.125f
#define ALPHA 0.1f
#define OUT0  (B_ * N_ * C_)  // 7090176 floats (out), then patch_attn

#define NB_CONV 7008          // MP_*768/4/256
#define NB_T1   1728          // (2304/32)*(768/32)
#define NB_T2   576           // (768/32)*(768/32)

typedef __attribute__((ext_vector_type(8))) short short8;
typedef __attribute__((ext_vector_type(4))) float f32x4;
typedef __hip_bfloat16 bf16;

__device__ __forceinline__ float exp2fast(float x) {
    return __builtin_amdgcn_exp2f(x);   // v_exp_f32 (base 2)
}

__device__ __forceinline__ void load16(const void* g, void* l) {
    __builtin_amdgcn_global_load_lds(
        (const __attribute__((address_space(1))) unsigned int*)g,
        (__attribute__((address_space(3))) unsigned int*)l, 16, 0, 0);
}

__device__ __forceinline__ f32x4 mfma16(short8 a, short8 b, f32x4 c) {
    return __builtin_amdgcn_mfma_f32_16x16x32_bf16(a, b, c, 0, 0, 0);
}

#define FENCE() asm volatile("" ::: "memory")
#define BARRIER() do { FENCE(); __builtin_amdgcn_s_barrier(); FENCE(); } while (0)

// ---------------- fused prep: conv_x + transpose(w_qkv) + transpose(w_proj)
__global__ __launch_bounds__(256) void prep(const float* __restrict__ x,
                                            bf16* __restrict__ xb,
                                            const float* __restrict__ wq,
                                            bf16* __restrict__ wqT,
                                            const float* __restrict__ wp,
                                            bf16* __restrict__ wpT) {
    __shared__ float tile[32][33];
    const int bid = blockIdx.x;
    if (bid < NB_CONV) {
        int idx = bid * 256 + threadIdx.x;   // one per 4 elements
        int m = idx / 192;
        bf16 tmp[4];
        if (m < M_) {
            float4 f = ((const float4*)x)[idx];
            tmp[0] = __float2bfloat16(f.x);
            tmp[1] = __float2bfloat16(f.y);
            tmp[2] = __float2bfloat16(f.z);
            tmp[3] = __float2bfloat16(f.w);
        } else {
            tmp[0] = tmp[1] = tmp[2] = tmp[3] = __float2bfloat16(0.f);
        }
        ((ushort4*)xb)[idx] = *(ushort4*)tmp;
        return;
    }
    const float* src; bf16* dst; int C, R, bx, by;
    if (bid < NB_CONV + NB_T1) {
        int r = bid - NB_CONV;
        bx = r % 72; by = r / 72; src = wq; dst = wqT; R = 768; C = QKVN;
    } else {
        int r = bid - NB_CONV - NB_T1;
        bx = r % 24; by = r / 24; src = wp; dst = wpT; R = 768; C = 768;
    }
    int cb = bx * 32, rb = by * 32;
    int tx = threadIdx.x & 31, ty = threadIdx.x >> 5;  // ty 0..7
    #pragma unroll
    for (int i = 0; i < 32; i += 8)
        tile[ty + i][tx] = src[(size_t)(rb + ty + i) * C + cb + tx];
    __syncthreads();
    #pragma unroll
    for (int i = 0; i < 32; i += 8)
        dst[(size_t)(cb + ty + i) * R + rb + tx] = __float2bfloat16(tile[tx][ty + i]);
}

// ---------------- 128x128 MFMA GEMM, BK=64, SINGLE-buffer, 4 blocks/CU.
// R8/R11-verified best (QKV 53.7-55.6us, MfmaUtil ~24%, VGPR 60).
// 256 threads = 4 waves (2M x 2N), per-wave 64x64 (acc[4][4]).  12 K-steps.
// Per step: {16 ds_read_b128 + 32 MFMA} -> BARRIER -> {stage(k+1) into the
// SAME buffer + vmcnt(0)} -> BARRIER.  4 independent blocks/CU cover each
// other's stage drains (R4/R5: TLP, not in-block pipelining, is what pays).
// R9 lesson: B must stay LDS-staged (direct per-lane global B-frags scatter
// 32 lines/load -> 98us).  R10 lesson: __launch_bounds__(512,6) capped VGPR
// at 85 -> acc spilled to scratch (VGPR=40, 1.6GB traffic, 414us); this
// kernel's (256,4) cap is 128 VGPR, actual 60, no spill.
// Race-freedom:
//  (a) barrier #1 after the MFMAs: every wave's ds_reads of the buffer were
//      consumed (compiler lgkm waits before MFMA) before any wave stages.
//  (b) vmcnt(0) + barrier #2 publishes all waves' staged slices.
// LDS swizzle: rows 128B; physical granule = logical ^ (row&7), applied via
// pre-swizzled GLOBAL source (linear gload_lds dest) + swizzled ds_read addr
// (conflict-verified: 23K).  Bijective XCD swizzle (m204).
__global__ __launch_bounds__(256, 4) void gemm128(const bf16* __restrict__ A,
                                                  const bf16* __restrict__ BT,
                                                  const float* __restrict__ bias,
                                                  bf16* __restrict__ q,
                                                  bf16* __restrict__ kk,
                                                  bf16* __restrict__ vt,
                                                  float* __restrict__ out,
                                                  int mode, int nby) {
    __shared__ __align__(16) char smem[35840];
    // A tile [128 rows][128B] at +0, B tile at +16384; Tt epilogue aliases all.

    const int nwg = gridDim.x;
    const int orig = blockIdx.x;
    const int xcd = orig & 7, ii = orig >> 3;
    const int qq = nwg >> 3, rr = nwg & 7;
    const int wg = (xcd < rr ? xcd * (qq + 1) : rr * (qq + 1) + (xcd - rr) * qq) + ii;
    const int mb = wg / nby;
    const int nb = wg - mb * nby;
    const int m0 = mb * 128, n0 = nb * 128;
    const int t = threadIdx.x, lane = t & 63, w = t >> 6;
    const int wr = w >> 1, wc = w & 1;
    const int r16 = lane & 15, quad = lane >> 4;

    f32x4 acc[4][4];
    #pragma unroll
    for (int i = 0; i < 4; i++)
        #pragma unroll
        for (int j = 0; j < 4; j++) acc[i][j] = (f32x4)(0.f);

    // staging: wave w writes tile bytes [w*4096, +4096) per operand, lane-linear.
    // LDS byte L = w*4096 + i*1024 + lane*16 -> row = w*32+i*8+(lane>>3),
    // phys granule = lane&7.  Source granule = (lane&7) ^ (row&7), row&7 = lane>>3.
    const int lrow = lane >> 3;
    const int clog = ((lane & 7) ^ lrow) << 4;
    const char* gA = (const char*)A  + (size_t)(m0 + w * 32 + lrow) * 1536 + clog;
    const char* gB = (const char*)BT + (size_t)(n0 + w * 32 + lrow) * 1536 + clog;

    auto stage = [&](int k2) {   // 8 loads: full A+B K-slab k2 -> the single buf
        const int kc = k2 * 128;
        #pragma unroll
        for (int i = 0; i < 4; i++) {
            char* dA = (char*)smem + w * 4096 + i * 1024;
            load16(gA + (size_t)i * 12288 + kc, dA);
            load16(gB + (size_t)i * 12288 + kc, dA + 16384);
        }
    };

    stage(0);
    asm volatile("s_waitcnt vmcnt(0)" ::: "memory");
    BARRIER();

    // read swizzle: logical granule g at row r sits at physical g ^ (r16&7)
    const int sw = r16 & 7;
    const int g0 = (quad ^ sw) << 4;          // kk0: logical granules 0..3
    const int g1 = ((quad ^ 4) ^ sw) << 4;    // kk1: logical granules 4..7

    #pragma unroll 1
    for (int k = 0; k < 12; k++) {
        const char* Ap = (const char*)smem + (wr * 64 + r16) * 128;
        const char* Bp = (const char*)smem + 16384 + (wc * 64 + r16) * 128;

        short8 a[4], b[4];
        #pragma unroll
        for (int mi = 0; mi < 4; mi++) a[mi] = *(const short8*)(Ap + mi * 2048 + g0);
        #pragma unroll
        for (int nj = 0; nj < 4; nj++) b[nj] = *(const short8*)(Bp + nj * 2048 + g0);
        __builtin_amdgcn_s_setprio(1);
        #pragma unroll
        for (int mi = 0; mi < 4; mi++)
            #pragma unroll
            for (int nj = 0; nj < 4; nj++)
                acc[mi][nj] = mfma16(a[mi], b[nj], acc[mi][nj]);
        __builtin_amdgcn_s_setprio(0);

        #pragma unroll
        for (int mi = 0; mi < 4; mi++) a[mi] = *(const short8*)(Ap + mi * 2048 + g1);
        #pragma unroll
        for (int nj = 0; nj < 4; nj++) b[nj] = *(const short8*)(Bp + nj * 2048 + g1);
        __builtin_amdgcn_s_setprio(1);
        #pragma unroll
        for (int mi = 0; mi < 4; mi++)
            #pragma unroll
            for (int nj = 0; nj < 4; nj++)
                acc[mi][nj] = mfma16(a[mi], b[nj], acc[mi][nj]);
        __builtin_amdgcn_s_setprio(0);

        BARRIER();                 // all waves' reads of the buffer retired
        if (k < 11) {
            stage(k + 1);          // overwrite the single buffer
            asm volatile("s_waitcnt vmcnt(0)" ::: "memory");
            BARRIER();             // publish all waves' slices
        }
    }

    float bs[4];
    #pragma unroll
    for (int nj = 0; nj < 4; nj++) bs[nj] = bias[n0 + wc * 64 + nj * 16 + r16];

    if (mode == 1) {
        #pragma unroll
        for (int mi = 0; mi < 4; mi++) {
            #pragma unroll
            for (int nj = 0; nj < 4; nj++) {
                #pragma unroll
                for (int r = 0; r < 4; r++) {
                    int m = m0 + wr * 64 + mi * 16 + quad * 4 + r;
                    if (m >= M_) continue;
                    int cc = n0 + wc * 64 + nj * 16 + r16;
                    out[(size_t)m * 768 + cc] = acc[mi][nj][r] + bs[nj];
                }
            }
        }
        return;
    }

    // ---- mode 0: pack C^T into Tt (col-major, pad 140), then scatter (proven)
    bf16* Tt = (bf16*)smem;                 // [128 cc][140 m], aliases the buffer
    #pragma unroll
    for (int mi = 0; mi < 4; mi++) {
        #pragma unroll
        for (int nj = 0; nj < 4; nj++) {
            bf16 pk[4];
            #pragma unroll
            for (int r = 0; r < 4; r++)
                pk[r] = __float2bfloat16(acc[mi][nj][r] + bs[nj]);
            int ccl = wc * 64 + nj * 16 + r16;
            int ml4 = wr * 64 + mi * 16 + quad * 4;
            *(uint2*)&Tt[ccl * 140 + ml4] = *(const uint2*)pk;
        }
    }
    __syncthreads();

    const int part = nb / 6;     // 0:q 1:k 2:v (128-col blocks, 6 per part)
    if (part < 2) {
        // q/k: thread = (half, row). dst rows contiguous across n for fixed (b,h).
        int nl = t & 127, half = t >> 7;
        int m = m0 + nl;
        if (m < M_) {
            int b = m / N_, n = m - b * N_;
            int h = (nb % 6) * 2 + half;
            bf16* dst = (part == 0 ? q : kk) + ((size_t)(b * H_ + h) * N_ + n) * 64;
            #pragma unroll
            for (int d8 = 0; d8 < 8; d8++) {
                bf16 tv[8];
                #pragma unroll
                for (int dd = 0; dd < 8; dd++)
                    tv[dd] = Tt[(half * 64 + d8 * 8 + dd) * 140 + nl];
                *(uint4*)(dst + d8 * 8) = *(const uint4*)tv;
            }
        }
    } else {
        // v: thread = (d-row, 64-col segment); runs contiguous in n with peeling
        int dr = t >> 1, seg = t & 1;
        int rem = (nb % 6) * 128 + dr;   // global v-col = h*64+d
        int h = rem >> 6, d = rem & 63;
        int mb2 = m0 + seg * 64;
        int b = mb2 / N_;
        int n = mb2 - b * N_;
        const bf16* src = Tt + dr * 140 + seg * 64;
        int i = 0;
        while (i < 64 && mb2 + i < M_) {
            if (n == N_) { b++; n = 0; }
            bf16* drow = vt + ((size_t)(b * H_ + h) * 64 + d) * NP_;
            if ((n & 7) == 0 && n + 8 <= N_ && i + 8 <= 64 && mb2 + i + 8 <= M_) {
                bf16 tv[8];
                #pragma unroll
                for (int dd = 0; dd < 8; dd++) tv[dd] = src[i + dd];
                *(uint4*)(drow + n) = *(const uint4*)tv;
                i += 8; n += 8;
            } else {
                drow[n] = src[i]; i++; n++;
            }
        }
    }
}

// ---------------- flash attention, MFMA, SINGLE-buffer K/V (R14).
// R13 post-mortem: __launch_bounds__(256,4) made the allocator squeeze to
// the 64-VGPR tier and SPILL (~40 regs re-touched per kt-iter): FETCH
// 21.6->75.9MB, WRITE 14.3->43.3MB, dur 54->104us.  Fix: plain (256) --
// R11's attn compiled spill-free at 112 VGPR; single-buffer state is
// smaller, so <=112 -> 4 waves/SIMD tier -> 16 waves/CU = 4 blocks/CU
// NATURALLY (LDS 32KB allows 5).  1024 slots >= 960 blocks: whole grid
// co-resident, R11's 1.25-round tail eliminated.
// Sync: compute -> __syncthreads (drains vmcnt + retires all K/V reads) ->
// stage(kt+1) same buffers -> __syncthreads (publishes).  Pb per-wave.
// Compute, swizzle, XCD remap (T1, R8-verified) bitwise identical to R11.
__global__ __launch_bounds__(256) void attn_mfma(const bf16* __restrict__ q,
                                                 const bf16* __restrict__ k,
                                                 const bf16* __restrict__ vt,
                                                 const float* __restrict__ aw,
                                                 bf16* __restrict__ ao,
                                                 float* __restrict__ patch) {
    __shared__ bf16 Kb[4096];       // 64 j-rows x 64 d, chunk-XOR swizzled
    __shared__ bf16 Vb[4096];       // 64 d-rows x 64 j, chunk-XOR swizzled
    __shared__ bf16 Pb[4][2048];    // per-wave 32x64 P strip
    // bijective XCD swizzle over 960 blocks: wg = (orig&7)*120 + (orig>>3);
    // bh = wg/5 (contiguous 24-head chunk per XCD), qt = wg%5 (co-XCD).
    const int orig = blockIdx.x;
    const int wg = (orig & 7) * 120 + (orig >> 3);
    const int bh = wg / 5, qt = wg - bh * 5;
    const int b = bh / H_, h = bh - b * H_;
    const int t = threadIdx.x, lane = t & 63, w = t >> 6;
    const int r16 = lane & 15, quad = lane >> 4;
    const float SC2 = SCALE * 1.44269504f;   // scale * log2(e)

    const bf16* kbp = k + (size_t)bh * N_ * 64;
    const bf16* vbp = vt + (size_t)bh * 64 * NP_;

    short8 qa0[2], qa1[2];
    #pragma unroll
    for (int mi = 0; mi < 2; mi++) {
        int qrow = qt * 128 + w * 32 + mi * 16 + r16;
        int qrc = (qrow < N_) ? qrow : (N_ - 1);
        const bf16* qp = q + ((size_t)bh * N_ + qrc) * 64 + quad * 8;
        qa0[mi] = *(const short8*)(qp);
        qa1[mi] = *(const short8*)(qp + 32);
    }

    f32x4 Oacc[2][4];
    #pragma unroll
    for (int mi = 0; mi < 2; mi++)
        #pragma unroll
        for (int d0 = 0; d0 < 4; d0++) Oacc[mi][d0] = (f32x4)(0.f);
    float lrow[2][4];
    #pragma unroll
    for (int mi = 0; mi < 2; mi++)
        #pragma unroll
        for (int rr = 0; rr < 4; rr++) lrow[mi][rr] = 0.f;

    const bool clsrow = (qt == 0) && (w == 0) && (quad == 0);

    auto stage = [&](int kt) {
        #pragma unroll
        for (int is = 0; is < 2; is++) {
            int base = is * 256 + w * 64;
            int slot = base + lane;
            int row = slot >> 3, pos = slot & 7;
            int c = pos ^ (row & 7);
            int jg = kt * 64 + row; if (jg > N_ - 1) jg = N_ - 1;
            load16(kbp + (size_t)jg * 64 + c * 8, &Kb[base * 8]);
        }
        #pragma unroll
        for (int is = 0; is < 2; is++) {
            int base = is * 256 + w * 64;
            int slot = base + lane;
            int row = slot >> 3, pos = slot & 7;
            int c = pos ^ (row & 7);
            load16(vbp + (size_t)row * NP_ + kt * 64 + c * 8, &Vb[base * 8]);
        }
    };

    stage(0);
    __syncthreads();          // drains vmcnt(0) + publishes tile 0

    for (int kt = 0; kt < 10; kt++) {
        f32x4 S[2][4];
        #pragma unroll
        for (int j0 = 0; j0 < 4; j0++) {
            int row = j0 * 16 + r16;
            const bf16* kpl = &Kb[row * 64];
            short8 kf0 = *(const short8*)(kpl + ((quad ^ (row & 7)) << 3));
            short8 kf1 = *(const short8*)(kpl + (((quad ^ 4) ^ (row & 7)) << 3));
            #pragma unroll
            for (int mi = 0; mi < 2; mi++) {
                f32x4 sa = (f32x4)(0.f);
                sa = mfma16(qa0[mi], kf0, sa);
                sa = mfma16(qa1[mi], kf1, sa);
                S[mi][j0] = sa;
            }
        }

        if (kt < 9) {
            #pragma unroll
            for (int mi = 0; mi < 2; mi++) {
                #pragma unroll
                for (int j0 = 0; j0 < 4; j0++) {
                    float wfac = 1.f;
                    if (mi == 0 && clsrow) {
                        int c = kt * 64 + j0 * 16 + r16;
                        if (c >= 1) {
                            patch[(size_t)bh * (N_ - 1) + (c - 1)] = S[0][j0][0] * SCALE;
                            wfac = aw[b * (N_ - 1) + (c - 1)] * ALPHA + (1.f - ALPHA);
                        }
                    }
                    #pragma unroll
                    for (int rr = 0; rr < 4; rr++) {
                        float v = S[mi][j0][rr] * SC2;
                        if (rr == 0) v *= wfac;
                        float p = exp2fast(v);
                        S[mi][j0][rr] = p;
                        lrow[mi][rr] += p;
                    }
                }
            }
        } else {
            #pragma unroll
            for (int mi = 0; mi < 2; mi++) {
                #pragma unroll
                for (int j0 = 0; j0 < 4; j0++) {
                    int c = kt * 64 + j0 * 16 + r16;
                    bool valid = (c < N_);
                    float wfac = 1.f;
                    if (mi == 0 && clsrow && valid) {
                        patch[(size_t)bh * (N_ - 1) + (c - 1)] = S[0][j0][0] * SCALE;
                        wfac = aw[b * (N_ - 1) + (c - 1)] * ALPHA + (1.f - ALPHA);
                    }
                    #pragma unroll
                    for (int rr = 0; rr < 4; rr++) {
                        float v = S[mi][j0][rr] * SC2;
                        if (rr == 0) v *= wfac;
                        float p = valid ? exp2fast(v) : 0.f;
                        S[mi][j0][rr] = p;
                        lrow[mi][rr] += p;
                    }
                }
            }
        }

        bf16* pw = &Pb[w][0];
        #pragma unroll
        for (int mi = 0; mi < 2; mi++) {
            #pragma unroll
            for (int j0 = 0; j0 < 4; j0++) {
                int cg = j0 * 2 + (r16 >> 3);
                #pragma unroll
                for (int rr = 0; rr < 4; rr++) {
                    int rp = mi * 16 + quad * 4 + rr;
                    pw[rp * 64 + ((cg ^ (rp & 7)) << 3) + (r16 & 7)] =
                        __float2bfloat16(S[mi][j0][rr]);
                }
            }
        }
        short8 pa0[2], pa1[2];
        #pragma unroll
        for (int mi = 0; mi < 2; mi++) {
            int rp = mi * 16 + r16;
            const bf16* pr = pw + rp * 64;
            pa0[mi] = *(const short8*)(pr + ((quad ^ (rp & 7)) << 3));
            pa1[mi] = *(const short8*)(pr + (((quad ^ 4) ^ (rp & 7)) << 3));
        }

        #pragma unroll
        for (int d0 = 0; d0 < 4; d0++) {
            int row = d0 * 16 + r16;
            const bf16* vpl = &Vb[row * 64];
            short8 vf0 = *(const short8*)(vpl + ((quad ^ (row & 7)) << 3));
            short8 vf1 = *(const short8*)(vpl + (((quad ^ 4) ^ (row & 7)) << 3));
            #pragma unroll
            for (int mi = 0; mi < 2; mi++) {
                Oacc[mi][d0] = mfma16(pa0[mi], vf0, Oacc[mi][d0]);
                Oacc[mi][d0] = mfma16(pa1[mi], vf1, Oacc[mi][d0]);
            }
        }

        __syncthreads();          // all waves' K/V reads retired
        if (kt < 9) {
            stage(kt + 1);        // overwrite the single buffers
            __syncthreads();      // drains vmcnt + publishes tile kt+1
        }
    }

    #pragma unroll
    for (int mi = 0; mi < 2; mi++) {
        #pragma unroll
        for (int rr = 0; rr < 4; rr++) {
            float l = lrow[mi][rr];
            l += __shfl_xor(l, 1);
            l += __shfl_xor(l, 2);
            l += __shfl_xor(l, 4);
            l += __shfl_xor(l, 8);
            int n = qt * 128 + w * 32 + mi * 16 + quad * 4 + rr;
            if (n >= N_) continue;
            float inv = 1.f / l;
            #pragma unroll
            for (int d0 = 0; d0 < 4; d0++) {
                ao[((size_t)(b * N_ + n) * H_ + h) * 64 + d0 * 16 + r16] =
                    __float2bfloat16(Oacc[mi][d0][rr] * inv);
            }
        }
    }
}

extern "C" void kernel_launch(void* const* d_in, const int* in_sizes, int n_in,
                              void* d_out, int out_size, void* d_ws, size_t ws_size,
                              hipStream_t stream) {
    const float* x      = (const float*)d_in[0];
    const float* aw     = (const float*)d_in[1];
    const float* w_qkv  = (const float*)d_in[2];
    const float* b_qkv  = (const float*)d_in[3];
    const float* w_proj = (const float*)d_in[4];
    const float* b_proj = (const float*)d_in[5];
    float* out = (float*)d_out;

    char* ws = (char*)d_ws;
    bf16* xbf    = (bf16*)(ws);                 // MP x 768 (aliased as ao later)
    bf16* wqkvT  = (bf16*)(ws + 14352384);      // 2304 x 768
    bf16* wprojT = (bf16*)(ws + 17891328);      // 768 x 768
    bf16* qv     = (bf16*)(ws + 19070976);      // (b,h,n,d)
    bf16* kv     = (bf16*)(ws + 33251328);      // (b,h,n,d)
    bf16* vt     = (bf16*)(ws + 47431680);      // (b,h,d,NP)  -> end 63160320
    bf16* ao     = xbf;                          // WAR-safe alias (stream order)

    prep<<<NB_CONV + NB_T1 + NB_T2, 256, 0, stream>>>(x, xbf, w_qkv, wqkvT, w_proj, wprojT);

    // 128^2 tiles: QKV = 73 m-tiles x 18 n-tiles; proj = 73 x 6
    gemm128<<<73 * 18, 256, 0, stream>>>(
        xbf, wqkvT, b_qkv, qv, kv, vt, nullptr, 0, 18);

    // attn: 1D grid, 960 blocks (bh x qt), XCD-swizzled inside the kernel
    attn_mfma<<<H_ * B_ * 5, 256, 0, stream>>>(qv, kv, vt, aw, ao, out + OUT0);

    gemm128<<<73 * 6, 256, 0, stream>>>(
        ao, wprojT, b_proj, nullptr, nullptr, nullptr, out, 1, 6);
}